// Round 5
// baseline (159.879 us; speedup 1.0000x reference)
//
#include <hip/hip_runtime.h>
#include <hip/hip_bf16.h>
#include <math.h>

// GeomAttention: B=2, L=S=2048, H=8, E=D=32, fp32 in/out.
// scores = (0.5*dot - 0.5*relu(qn2*kn2 - dot^2))/sqrt(E); softmax over S; out = attn@V.
// Round 5: barrier-free K-loop. Pre-kernel materializes bf16 hi/lo K, bf16 V^T, fp32 kn2
// in d_ws; main kernel reads MFMA frags direct from global (L1/L2-hot), only per-wave
// sP LDS round-trip remains. In-block split-K (2 halves x 4 waves), combine at end.

#define NB 2
#define NL 2048
#define NS 2048
#define NH 8
#define NBH 16
#define KT 64
#define HK 1024
#define NTILE 16
#define CSC 0.12751742f  // 0.5 / sqrt(32) * log2(e)

#define WS_KN2_OFF 0
#define WS_KHKL_OFF (131072)                  // 16*2048 floats
#define WS_VT_OFF (131072 + 4194304)          // + 16*2048*64 u16
#define WS_NEED (131072 + 4194304 + 2097152)  // + 16*32*2048 u16 = 6,422,528 B

typedef float f32x4 __attribute__((ext_vector_type(4)));
typedef short s16x8 __attribute__((ext_vector_type(8)));
typedef unsigned short u16;

__device__ inline unsigned pk2(float a, float b) {  // bf16(a)|bf16(b)<<16, RNE
    __hip_bfloat162 t = __float22bfloat162_rn(make_float2(a, b));
    union { __hip_bfloat162 h; unsigned u; } cv;
    cv.h = t;
    return cv.u;
}
template <int CTRL>
__device__ inline float dpp_add(float x) {
    return x + __int_as_float(__builtin_amdgcn_mov_dpp(__float_as_int(x), CTRL, 0xF, 0xF, false));
}

// ---- pre-kernel (full): K -> bf16 hi/lo [key][2][32], V -> bf16 V^T [d][s], kn2 fp32 ----
__global__ __launch_bounds__(256) void pre_full(const float* __restrict__ K,
                                                const float* __restrict__ V,
                                                float* __restrict__ kn2w,
                                                u16* __restrict__ khkl,
                                                u16* __restrict__ vtw) {
    __shared__ float Vf[64][36];
    const int T = threadIdx.x;
    const int bh = blockIdx.x >> 5, stile = blockIdx.x & 31;
    const int b = bh >> 3, h = bh & 7;
    const int s0 = stile * 64;
    const int sk = T >> 2, kc = (T & 3) * 8;

    const float* kp = K + ((size_t)((b * NS + s0 + sk) * NH + h)) * 32 + kc;
    float4 f0 = *(const float4*)kp, f1 = *(const float4*)(kp + 4);
    float kx[8] = {f0.x, f0.y, f0.z, f0.w, f1.x, f1.y, f1.z, f1.w};
    unsigned hh[4], ll[4];
    float kn2p = 0.f;
#pragma unroll
    for (int i = 0; i < 4; i++) {
        float x0 = kx[2 * i], x1 = kx[2 * i + 1];
        kn2p = fmaf(x0, x0, kn2p);
        kn2p = fmaf(x1, x1, kn2p);
        unsigned h01 = pk2(x0, x1);
        hh[i] = h01;
        float h0 = __uint_as_float(h01 << 16);
        float h1 = __uint_as_float(h01 & 0xffff0000u);
        ll[i] = pk2(x0 - h0, x1 - h1);
    }
    u16* kd = khkl + ((size_t)(bh * NS + s0 + sk)) * 64 + kc;
    *(uint4*)kd = make_uint4(hh[0], hh[1], hh[2], hh[3]);
    *(uint4*)(kd + 32) = make_uint4(ll[0], ll[1], ll[2], ll[3]);
    kn2p = dpp_add<0xB1>(kn2p);
    kn2p = dpp_add<0x4E>(kn2p);
    if ((T & 3) == 0) kn2w[bh * NS + s0 + sk] = kn2p;

    const float* vp = V + ((size_t)((b * NS + s0 + sk) * NH + h)) * 32 + kc;
    float4 g0 = *(const float4*)vp, g1 = *(const float4*)(vp + 4);
    *(float4*)&Vf[sk][kc] = g0;
    *(float4*)&Vf[sk][kc + 4] = g1;
    __syncthreads();
    const int dr = T >> 3, sc8 = (T & 7) * 8;
    float vv[8];
#pragma unroll
    for (int i = 0; i < 8; i++) vv[i] = Vf[sc8 + i][dr];
    *(uint4*)(vtw + ((size_t)(bh * 32 + dr)) * NS + s0 + sc8) =
        make_uint4(pk2(vv[0], vv[1]), pk2(vv[2], vv[3]), pk2(vv[4], vv[5]), pk2(vv[6], vv[7]));
}

// ---- pre-kernel (fallback): kn2 only ----
__global__ __launch_bounds__(256) void kn2_kernel(const float* __restrict__ K,
                                                  float* __restrict__ kn2w) {
    int tid = blockIdx.x * blockDim.x + threadIdx.x;  // (b*NS+s)*NH + h
    const float* kp = K + (size_t)tid * 32;
    float s = 0.f;
#pragma unroll
    for (int e = 0; e < 32; e += 4) {
        float4 t = *(const float4*)(kp + e);
        s = fmaf(t.x, t.x, s);
        s = fmaf(t.y, t.y, s);
        s = fmaf(t.z, t.z, s);
        s = fmaf(t.w, t.w, s);
    }
    const int h = tid & 7, srow = (tid >> 3) & 2047, b = tid >> 14;
    kn2w[((b << 3) + h) * NS + srow] = s;
}

// ---- main kernel: no __syncthreads in the K-loop ----
template <bool PRE>
__global__ __launch_bounds__(512, 4) void geom_attn(
    const float* __restrict__ Q, const float* __restrict__ K,
    const float* __restrict__ V, const float* __restrict__ kn2w,
    const u16* __restrict__ khkl, const u16* __restrict__ vtw,
    float* __restrict__ O) {
    __shared__ union {
        u16 sP[8][16][64];  // per-wave P^T round-trip, swizzled
        struct { float acc[8][32][17]; float m[8][16]; float l[8][16]; } c;
    } u;

    const int T = threadIdx.x;
    const int lane = T & 63, wave = T >> 6;
    const int g = lane >> 4, lc = lane & 15, g8 = g * 8;
    const int half = wave >> 2;
    const int qt = blockIdx.x & 31;
    const int bh = blockIdx.x >> 5;
    const int b = bh >> 3, h = bh & 7;
    const int qw = qt * 64 + (wave & 3) * 16;
    const int kb0 = half * HK;

    // ---- Q fragments (B-operand; hi/lo bf16) + exact qn2, in-lane ----
    const float* qrow = Q + ((size_t)((b * NL + qw + lc) * NH + h)) * 32 + g8;
    float4 qa = *(const float4*)qrow, qb = *(const float4*)(qrow + 4);
    float q8[8] = {qa.x, qa.y, qa.z, qa.w, qb.x, qb.y, qb.z, qb.w};
    union { unsigned u4[4]; s16x8 v; } qh_, ql_;
    float qn2 = 0.f;
#pragma unroll
    for (int i = 0; i < 4; i++) {
        float x0 = q8[2 * i], x1 = q8[2 * i + 1];
        qn2 = fmaf(x0, x0, qn2);
        qn2 = fmaf(x1, x1, qn2);
        unsigned h01 = pk2(x0, x1);
        qh_.u4[i] = h01;
        float h0 = __uint_as_float(h01 << 16);
        float h1 = __uint_as_float(h01 & 0xffff0000u);
        ql_.u4[i] = pk2(x0 - h0, x1 - h1);
    }
    const s16x8 qh = qh_.v, ql = ql_.v;
    qn2 += __shfl_xor(qn2, 16);
    qn2 += __shfl_xor(qn2, 32);  // qn2 of query lc in every lane

    const float* kn2b = kn2w + (size_t)bh * NS + kb0;
    const u16* khb = PRE ? khkl + ((size_t)(bh * NS + kb0)) * 64 : nullptr;
    const u16* vtb = PRE ? vtw + ((size_t)bh * 32) * NS + kb0 : nullptr;
    const float* kf = K + ((size_t)((b * NS + kb0) * NH + h)) * 32;
    const float* vf = V + ((size_t)((b * NS + kb0) * NH + h)) * 32;

    s16x8 ones;
#pragma unroll
    for (int i = 0; i < 8; i++) ones[i] = (short)0x3F80;  // bf16 1.0

    f32x4 acc0 = {0.f, 0.f, 0.f, 0.f}, acc1 = {0.f, 0.f, 0.f, 0.f};
    float m = -1e30f, l = 0.f;
    const f32x4 z = {0.f, 0.f, 0.f, 0.f};

    for (int t = 0; t < NTILE; ++t) {
        const int kl64 = t * 64;
        // ---- A-frags (K hi/lo) and V^T frags: issued up front, long latency ----
        s16x8 kh[4], klo[4], va[4];
        f32x4 kn2v[4];
        if constexpr (PRE) {
#pragma unroll
            for (int st = 0; st < 4; st++) {
                const u16* kp = khb + (size_t)(kl64 + 16 * st + lc) * 64 + g8;
                kh[st] = *(const s16x8*)kp;
                klo[st] = *(const s16x8*)(kp + 32);
            }
            va[0] = *(const s16x8*)(vtb + (size_t)lc * NS + kl64 + g8);
            va[1] = *(const s16x8*)(vtb + (size_t)lc * NS + kl64 + 32 + g8);
            va[2] = *(const s16x8*)(vtb + (size_t)(lc + 16) * NS + kl64 + g8);
            va[3] = *(const s16x8*)(vtb + (size_t)(lc + 16) * NS + kl64 + 32 + g8);
        } else {
#pragma unroll
            for (int st = 0; st < 4; st++) {
                const float* kp = kf + (size_t)(kl64 + 16 * st + lc) * 256 + g8;
                float4 f0 = *(const float4*)kp, f1 = *(const float4*)(kp + 4);
                float kx[8] = {f0.x, f0.y, f0.z, f0.w, f1.x, f1.y, f1.z, f1.w};
                union { unsigned u4[4]; s16x8 v; } H, L;
#pragma unroll
                for (int i = 0; i < 4; i++) {
                    unsigned h01 = pk2(kx[2 * i], kx[2 * i + 1]);
                    H.u4[i] = h01;
                    float h0 = __uint_as_float(h01 << 16);
                    float h1 = __uint_as_float(h01 & 0xffff0000u);
                    L.u4[i] = pk2(kx[2 * i] - h0, kx[2 * i + 1] - h1);
                }
                kh[st] = H.v;
                klo[st] = L.v;
            }
#pragma unroll
            for (int q2 = 0; q2 < 4; q2++) {
                const int dd = (q2 >> 1) ? lc + 16 : lc;
                const int ko = (q2 & 1) * 32 + g8;
                float vv[8];
#pragma unroll
                for (int j = 0; j < 8; j++) vv[j] = vf[(size_t)(kl64 + ko + j) * 256 + dd];
                union { unsigned u4[4]; s16x8 v; } X;
#pragma unroll
                for (int i = 0; i < 4; i++) X.u4[i] = pk2(vv[2 * i], vv[2 * i + 1]);
                va[q2] = X.v;
            }
        }
#pragma unroll
        for (int st = 0; st < 4; st++)
            kn2v[st] = *(const f32x4*)(kn2b + kl64 + 16 * st + 4 * g);

        // ---- S^T = K·Q^T: 3-MFMA hi/lo per 16-key subtile ----
        f32x4 d[4];
#pragma unroll
        for (int st = 0; st < 4; st++) {
            f32x4 dd = __builtin_amdgcn_mfma_f32_16x16x32_bf16(klo[st], qh, z, 0, 0, 0);
            dd = __builtin_amdgcn_mfma_f32_16x16x32_bf16(kh[st], ql, dd, 0, 0, 0);
            dd = __builtin_amdgcn_mfma_f32_16x16x32_bf16(kh[st], qh, dd, 0, 0, 0);
            d[st] = dd;  // C[key=16st+4g+r][query=lc]
        }

        // ---- scores: sc' = d - relu(c - d^2) = min(d, d + (d^2 - c)) ----
        float sc[4][4];
#pragma unroll
        for (int st = 0; st < 4; st++)
#pragma unroll
            for (int r = 0; r < 4; r++) {
                float dd = d[st][r];
                float c = qn2 * kn2v[st][r];
                sc[st][r] = fminf(dd, fmaf(dd, dd, -c) + dd);
            }

        // ---- online softmax (CSC folded into exp2 args) ----
        float x0 = fmaxf(fmaxf(sc[0][0], sc[0][1]), fmaxf(sc[0][2], sc[0][3]));
        float x1 = fmaxf(fmaxf(sc[1][0], sc[1][1]), fmaxf(sc[1][2], sc[1][3]));
        float x2 = fmaxf(fmaxf(sc[2][0], sc[2][1]), fmaxf(sc[2][2], sc[2][3]));
        float x3 = fmaxf(fmaxf(sc[3][0], sc[3][1]), fmaxf(sc[3][2], sc[3][3]));
        float tm = fmaxf(fmaxf(x0, x1), fmaxf(x2, x3));
        tm = fmaxf(tm, __shfl_xor(tm, 16));
        tm = fmaxf(tm, __shfl_xor(tm, 32));
        const float nm = fmaxf(m, tm);
        const float negmC = -nm * CSC;
        const float al = __builtin_amdgcn_exp2f(fmaf(m, CSC, negmC));
        m = nm;
        float p[4][4];
#pragma unroll
        for (int st = 0; st < 4; st++)
#pragma unroll
            for (int r = 0; r < 4; r++)
                p[st][r] = __builtin_amdgcn_exp2f(fmaf(sc[st][r], CSC, negmC));

        // ---- P^T -> per-wave LDS (swizzled, conflict-free), own-wave round-trip ----
#pragma unroll
        for (int st = 0; st < 4; st++) {
            const int off = (((2 * st + (g >> 1)) ^ (lc & 7)) << 3) + ((g & 1) << 2);
            *(uint2*)&u.sP[wave][lc][off] =
                make_uint2(pk2(p[st][0], p[st][1]), pk2(p[st][2], p[st][3]));
        }
        __builtin_amdgcn_s_waitcnt(0xC07F);  // lgkmcnt(0)
        s16x8 pb0 = *(s16x8*)&u.sP[wave][lc][(g ^ (lc & 7)) << 3];
        s16x8 pb1 = *(s16x8*)&u.sP[wave][lc][((4 + g) ^ (lc & 7)) << 3];

        // ---- rescale + PV + l via ones-MFMA ----
        acc0 *= al;
        acc1 *= al;
        acc0 = __builtin_amdgcn_mfma_f32_16x16x32_bf16(va[0], pb0, acc0, 0, 0, 0);
        acc0 = __builtin_amdgcn_mfma_f32_16x16x32_bf16(va[1], pb1, acc0, 0, 0, 0);
        acc1 = __builtin_amdgcn_mfma_f32_16x16x32_bf16(va[2], pb0, acc1, 0, 0, 0);
        acc1 = __builtin_amdgcn_mfma_f32_16x16x32_bf16(va[3], pb1, acc1, 0, 0, 0);
        f32x4 lt = __builtin_amdgcn_mfma_f32_16x16x32_bf16(ones, pb0, z, 0, 0, 0);
        lt = __builtin_amdgcn_mfma_f32_16x16x32_bf16(ones, pb1, lt, 0, 0, 0);
        l = fmaf(l, al, lt[0]);
    }

    // ---- epilogue: publish partials (LDS reused), combine two key-halves ----
    __syncthreads();  // all waves done with sP before union reuse
#pragma unroll
    for (int r = 0; r < 4; r++) {
        u.c.acc[wave][4 * g + r][lc] = acc0[r];       // O^T[d][q]
        u.c.acc[wave][16 + 4 * g + r][lc] = acc1[r];
    }
    if (lane < 16) {
        u.c.m[wave][lc] = m;
        u.c.l[wave][lc] = l;
    }
    __syncthreads();

    const int q = T >> 3, dq = (T & 7) * 4, qr = q & 15;
    const int w0 = q >> 4, w1 = w0 + 4;
    float m0 = u.c.m[w0][qr], m1 = u.c.m[w1][qr];
    float l0 = u.c.l[w0][qr], l1 = u.c.l[w1][qr];
    float mf = fmaxf(m0, m1);
    float e0 = __builtin_amdgcn_exp2f(fmaf(m0, CSC, -mf * CSC));
    float e1 = __builtin_amdgcn_exp2f(fmaf(m1, CSC, -mf * CSC));
    float inv = 1.f / fmaf(l1, e1, l0 * e0);
    e0 *= inv;
    e1 *= inv;
    float4 o;
    o.x = u.c.acc[w0][dq + 0][qr] * e0 + u.c.acc[w1][dq + 0][qr] * e1;
    o.y = u.c.acc[w0][dq + 1][qr] * e0 + u.c.acc[w1][dq + 1][qr] * e1;
    o.z = u.c.acc[w0][dq + 2][qr] * e0 + u.c.acc[w1][dq + 2][qr] * e1;
    o.w = u.c.acc[w0][dq + 3][qr] * e0 + u.c.acc[w1][dq + 3][qr] * e1;
    *(float4*)(O + ((size_t)((b * NL + qt * 64 + q) * NH + h)) * 32 + dq) = o;
}

extern "C" void kernel_launch(void* const* d_in, const int* in_sizes, int n_in,
                              void* d_out, int out_size, void* d_ws, size_t ws_size,
                              hipStream_t stream) {
    const float* Q = (const float*)d_in[0];
    const float* K = (const float*)d_in[1];
    const float* V = (const float*)d_in[2];
    float* O = (float*)d_out;
    float* kn2w = (float*)((char*)d_ws + WS_KN2_OFF);
    u16* khkl = (u16*)((char*)d_ws + WS_KHKL_OFF);
    u16* vtw = (u16*)((char*)d_ws + WS_VT_OFF);

    if (ws_size >= (size_t)WS_NEED) {
        pre_full<<<NBH * 32, 256, 0, stream>>>(K, V, kn2w, khkl, vtw);
        geom_attn<true><<<NBH * 32, 512, 0, stream>>>(Q, K, V, kn2w, khkl, vtw, O);
    } else {
        kn2_kernel<<<(NB * NS * NH) / 256, 256, 0, stream>>>(K, kn2w);
        geom_attn<false><<<NBH * 32, 512, 0, stream>>>(Q, K, V, kn2w, khkl, vtw, O);
    }
}